// Round 14
// baseline (353.457 us; speedup 1.0000x reference)
//
#include <hip/hip_runtime.h>

#define FDIM 128
#define BN_EPS 1e-5f

#define NPB 32           // nodes per bucket (dst >> 5)
#define NB_CAP 4096      // supports N up to 131072 (< 2^26 so src packs in 26 bits)
#define BIN_CHUNK 4096   // edges per bin block (R7 form)
#define AGG_CHUNK 1024   // edges per aggregate chunk (LDS sort buffer)

typedef short v8s __attribute__((ext_vector_type(8)));
typedef float v4f __attribute__((ext_vector_type(4)));
typedef float floatx2 __attribute__((ext_vector_type(2)));

#if defined(__has_builtin)
#if __has_builtin(__builtin_amdgcn_cvt_pk_f32_fp8) && __has_builtin(__builtin_amdgcn_cvt_pk_fp8_f32)
#define HAVE_FP8_CVT 1
#endif
#endif
#ifndef HAVE_FP8_CVT
#define HAVE_FP8_CVT 0
#endif

__device__ __forceinline__ float bf2f(unsigned short u) {
    union { unsigned int i; float f; } v; v.i = ((unsigned int)u) << 16; return v.f;
}
__device__ __forceinline__ unsigned short f2bf(float f) {
    union { float f2; unsigned int i; } v; v.f2 = f;
    unsigned int r = v.i + 0x7FFFu + ((v.i >> 16) & 1u);  // RNE
    return (unsigned short)(r >> 16);
}

// ----- OCP e4m3fn encode/decode (manual fallback; HW cvt when available) ----
__device__ __forceinline__ unsigned char f2fp8(float f) {
    union { float f; unsigned u; } v; v.f = f;
    unsigned s = (v.u >> 24) & 0x80u;
    v.u &= 0x7FFFFFFFu;
    float a = v.f;
    if (!(a < 448.f)) a = 448.f;
    v.f = a;
    unsigned r;
    if (v.u < 0x3C800000u) {              // a < 2^-6 : subnormal (value = q * 2^-9)
        r = (unsigned)(int)(a * 512.0f + 0.5f);        // 0..8 (8 == min normal)
    } else {
        unsigned t = v.u + 0x7FFFFu + ((v.u >> 20) & 1u);  // RNE to 3-bit mantissa
        int e = (int)(t >> 23) - 120;
        unsigned m = (t >> 20) & 7u;
        if (e > 15) { e = 15; m = 6; }    // clamp to 448
        r = ((unsigned)e << 3) | m;
    }
    return (unsigned char)(r | s);
}
__device__ __forceinline__ float fp82f(unsigned int u) {
    u &= 0xFFu;
    unsigned em = u & 0x7Fu;
    union { unsigned u; float f; } v;
    v.u = ((u & 0x80u) << 24) | ((em + 960u) << 20);
    float sub = (float)(int)em * 0.001953125f;         // em * 2^-9
    if (u & 0x80u) sub = -sub;
    return (em < 8u) ? sub : v.f;
}
__device__ __forceinline__ unsigned int pack_fp8x4(float f0, float f1, float f2, float f3) {
#if HAVE_FP8_CVT
    unsigned int r = (unsigned int)__builtin_amdgcn_cvt_pk_fp8_f32(f0, f1, 0, false);
    r = (unsigned int)__builtin_amdgcn_cvt_pk_fp8_f32(f2, f3, (int)r, true);
    return r;
#else
    return (unsigned int)f2fp8(f0) | ((unsigned int)f2fp8(f1) << 8) |
           ((unsigned int)f2fp8(f2) << 16) | ((unsigned int)f2fp8(f3) << 24);
#endif
}

// ---------------------------------------------------------------------------
// Detect dtypes (wave-parallel); build Wc (bf16 [128][256]), f32 params;
// zero cursors, col_sum/col_sq and bcnt/bcur.
// flags[0]=ei_is_int64, flags[1]=floats_are_f32, flags[4]/[5]=alloc cursors.
// ---------------------------------------------------------------------------
__global__ __launch_bounds__(1024) void detect_convert_kernel(
    const unsigned int* __restrict__ xw, const int* __restrict__ ei,
    const void* __restrict__ Wl, const void* __restrict__ bl,
    const void* __restrict__ Wr, const void* __restrict__ gm,
    const void* __restrict__ bt,
    unsigned short* __restrict__ Wc,
    float* __restrict__ Wl32, float* __restrict__ Wr32,
    float* __restrict__ bl32, float* __restrict__ gm32, float* __restrict__ bt32,
    float* __restrict__ col_sum,        // 2*FDIM floats
    int* __restrict__ bcnt,             // 2*NB_CAP ints (bcnt+bcur contiguous)
    int* __restrict__ flags)
{
    __shared__ int s_any, s_cnt, s_f32;
    int tid = threadIdx.x;
    if (tid == 0) { s_any = 0; s_cnt = 0; }
    __syncthreads();
    if (tid < 128) {
        atomicOr(&s_any, ei[2 * tid + 1]);
        unsigned short h = (unsigned short)(xw[tid] & 0xFFFFu);
        int e = (h >> 7) & 0xFF;
        atomicAdd(&s_cnt, (h == 0 || (e >= 116 && e <= 133)) ? 1 : 0);
    }
    __syncthreads();
    if (tid == 0) {
        flags[0] = (s_any == 0) ? 1 : 0;
        int f32 = (s_cnt < 64) ? 1 : 0;
        flags[1] = f32;
        s_f32 = f32;
        flags[4] = 0;
        flags[5] = 0;
    }
    for (int i = tid; i < 2 * NB_CAP; i += blockDim.x) bcnt[i] = 0;
    if (tid < 2 * FDIM) col_sum[tid] = 0.0f;
    __syncthreads();
    int f32 = s_f32;
    for (int i = tid; i < FDIM * FDIM; i += blockDim.x) {
        int d = i >> 7, k = i & 127;
        float wl = f32 ? ((const float*)Wl)[i] : bf2f(((const unsigned short*)Wl)[i]);
        float wr = f32 ? ((const float*)Wr)[i] : bf2f(((const unsigned short*)Wr)[i]);
        Wl32[i] = wl;
        Wr32[i] = wr;
        Wc[d * 256 + k]       = f2bf(wl);
        Wc[d * 256 + 128 + k] = f2bf(wr);
    }
    if (tid < FDIM) {
        bl32[tid] = f32 ? ((const float*)bl)[tid] : bf2f(((const unsigned short*)bl)[tid]);
        gm32[tid] = f32 ? ((const float*)gm)[tid] : bf2f(((const unsigned short*)gm)[tid]);
        bt32[tid] = f32 ? ((const float*)bt)[tid] : bf2f(((const unsigned short*)bt)[tid]);
    }
}

__device__ __forceinline__ int edge_at(const int* ei, long long pos, int is64) {
    return is64 ? ei[2 * pos] : ei[pos];
}

// ---------------------------------------------------------------------------
// Fused: x -> bf16 copy (f32 input only; bf16 input read directly by gemm)
// + fp8 gather-table (blocks [0, cblocks)) + bucket histogram (blocks
// [cblocks, cblocks+256)). x8 lives in d_out (scratch until final BN).
// ---------------------------------------------------------------------------
__global__ __launch_bounds__(256) void convert_count_kernel(
    const void* __restrict__ xv, unsigned short* __restrict__ x_bf,
    uint2* __restrict__ x8,
    const int* __restrict__ ei, int* __restrict__ bcnt,
    const int* __restrict__ flags, long long n8, int E, int N, int NB,
    int cblocks)
{
    __shared__ int lcnt[NB_CAP];
    if ((int)blockIdx.x < cblocks) {
        long long i = (long long)blockIdx.x * 256 + threadIdx.x;
        if (i >= n8) return;
        float f0, f1, f2, f3, f4, f5, f6, f7;
        if (flags[1]) {
            const float4* xf = (const float4*)xv;
            float4 a = xf[i * 2], b = xf[i * 2 + 1];
            f0 = a.x; f1 = a.y; f2 = a.z; f3 = a.w;
            f4 = b.x; f5 = b.y; f6 = b.z; f7 = b.w;
            uint4 p;
            p.x = (unsigned int)f2bf(f0) | ((unsigned int)f2bf(f1) << 16);
            p.y = (unsigned int)f2bf(f2) | ((unsigned int)f2bf(f3) << 16);
            p.z = (unsigned int)f2bf(f4) | ((unsigned int)f2bf(f5) << 16);
            p.w = (unsigned int)f2bf(f6) | ((unsigned int)f2bf(f7) << 16);
            ((uint4*)x_bf)[i] = p;
        } else {
            uint4 p = ((const uint4*)xv)[i];
            // no x_bf store: gemm reads original x directly (same layout)
            f0 = bf2f((unsigned short)(p.x & 0xFFFF)); f1 = bf2f((unsigned short)(p.x >> 16));
            f2 = bf2f((unsigned short)(p.y & 0xFFFF)); f3 = bf2f((unsigned short)(p.y >> 16));
            f4 = bf2f((unsigned short)(p.z & 0xFFFF)); f5 = bf2f((unsigned short)(p.z >> 16));
            f6 = bf2f((unsigned short)(p.w & 0xFFFF)); f7 = bf2f((unsigned short)(p.w >> 16));
        }
        uint2 q;
        q.x = pack_fp8x4(f0, f1, f2, f3);
        q.y = pack_fp8x4(f4, f5, f6, f7);
        x8[i] = q;
    } else {
        int cb = (int)blockIdx.x - cblocks;     // 0..255
        for (int i = threadIdx.x; i < NB; i += 256) lcnt[i] = 0;
        __syncthreads();
        int is64 = flags[0];
        for (long long e = (long long)cb * 256 + threadIdx.x; e < E;
             e += 256LL * 256) {
            int src = edge_at(ei, e, is64);
            int dst = edge_at(ei, (long long)E + e, is64);
            if ((unsigned)src >= (unsigned)N || (unsigned)dst >= (unsigned)N) continue;
            atomicAdd(&lcnt[dst >> 5], 1);
        }
        __syncthreads();
        for (int i = threadIdx.x; i < NB; i += 256) {
            int c = lcnt[i];
            if (c) atomicAdd(&bcnt[i], c);
        }
    }
}

// ---------------------------------------------------------------------------
__global__ __launch_bounds__(256) void zero_kernel(float* __restrict__ z, long long n)
{
    long long i = (long long)blockIdx.x * 256 + threadIdx.x;
    long long stride = (long long)gridDim.x * 256;
    for (; i < n; i += stride) z[i] = 0.0f;
}

// ---------------------------------------------------------------------------
// Bucket phase 2: order-free range allocation over NB buckets (wave scan +
// one atomic per wave). Disjoint ranges; global order irrelevant.
// ---------------------------------------------------------------------------
__global__ __launch_bounds__(256) void offset_kernel(
    const int* __restrict__ cnt, int* __restrict__ row_start,
    int* __restrict__ counter, int N)
{
    int i = blockIdx.x * 256 + threadIdx.x;
    int lane = threadIdx.x & 63;
    int v0 = (i < N) ? cnt[i] : 0;
    int v = v0;
    #pragma unroll
    for (int off = 1; off < 64; off <<= 1) {
        int t = __shfl_up(v, off, 64);
        if (lane >= off) v += t;
    }
    int total = __shfl(v, 63, 64);
    int base = 0;
    if (lane == 0) base = atomicAdd(counter, total);
    base = __shfl(base, 0, 64);
    if (i < N) row_start[i] = base + v - v0;
}

// ---------------------------------------------------------------------------
// Bucket phase 3 (R7 form — measured best): chunk staged in LDS (src/dst)
// so ei is read ONCE; count -> reserve one range per (block,bucket) ->
// scatter packed (dst_local<<26)|src from LDS.
// ---------------------------------------------------------------------------
__global__ __launch_bounds__(256) void bin_kernel(
    const int* __restrict__ ei, const int* __restrict__ bst,
    int* __restrict__ bcur, unsigned int* __restrict__ bbuf,
    const int* __restrict__ flags, int E, int N, int NB)
{
    __shared__ int lcnt[NB_CAP];
    __shared__ int lbase[NB_CAP];
    __shared__ int ssrc[BIN_CHUNK];
    __shared__ int sdst[BIN_CHUNK];
    for (int i = threadIdx.x; i < NB; i += 256) lcnt[i] = 0;
    __syncthreads();
    long long e0 = (long long)blockIdx.x * BIN_CHUNK;
    int is64 = flags[0];
    for (int j = 0; j < BIN_CHUNK / 256; ++j) {
        int idx = j * 256 + threadIdx.x;
        long long e = e0 + idx;
        int d = -1, s = 0;
        if (e < E) {
            s = edge_at(ei, e, is64);
            int dd = edge_at(ei, (long long)E + e, is64);
            if ((unsigned)s < (unsigned)N && (unsigned)dd < (unsigned)N) d = dd;
        }
        ssrc[idx] = s;
        sdst[idx] = d;
        if (d >= 0) atomicAdd(&lcnt[d >> 5], 1);
    }
    __syncthreads();
    for (int i = threadIdx.x; i < NB; i += 256) {
        int c = lcnt[i];
        lbase[i] = c ? atomicAdd(&bcur[i], c) : 0;
    }
    __syncthreads();
    for (int j = 0; j < BIN_CHUNK / 256; ++j) {
        int idx = j * 256 + threadIdx.x;
        int d = sdst[idx];
        if (d < 0) continue;
        int b = d >> 5;
        int pos = atomicAdd(&lbase[b], 1);
        bbuf[bst[b] + pos] = ((unsigned int)(d & 31) << 26) | (unsigned int)ssrc[idx];
    }
}

#if HAVE_FP8_CVT
#define ACC8(nl, w) do { \
    floatx2 _a = __builtin_amdgcn_cvt_pk_f32_fp8((int)(w).x, false); \
    floatx2 _b = __builtin_amdgcn_cvt_pk_f32_fp8((int)(w).x, true);  \
    floatx2 _c = __builtin_amdgcn_cvt_pk_f32_fp8((int)(w).y, false); \
    floatx2 _d = __builtin_amdgcn_cvt_pk_f32_fp8((int)(w).y, true);  \
    acc[nl][0] += _a.x; acc[nl][1] += _a.y; acc[nl][2] += _b.x; acc[nl][3] += _b.y; \
    acc[nl][4] += _c.x; acc[nl][5] += _c.y; acc[nl][6] += _d.x; acc[nl][7] += _d.y; \
} while (0)
#else
#define ACC8(nl, w) do { \
    acc[nl][0] += fp82f((w).x);       acc[nl][1] += fp82f((w).x >> 8);  \
    acc[nl][2] += fp82f((w).x >> 16); acc[nl][3] += fp82f((w).x >> 24); \
    acc[nl][4] += fp82f((w).y);       acc[nl][5] += fp82f((w).y >> 8);  \
    acc[nl][6] += fp82f((w).y >> 16); acc[nl][7] += fp82f((w).y >> 24); \
} while (0)
#endif

// ---------------------------------------------------------------------------
// Bucket phase 4 (single dispatch): one block (256 thr, 4 waves) per
// 32-node bucket, REGISTER accumulation; gathers 128B fp8 rows. At the
// random-access fabric floor (R7 measured).
// ---------------------------------------------------------------------------
__global__ __launch_bounds__(256) void bucket_agg_kernel(
    const uint2* __restrict__ x8,             // fp8 table [N][16] uint2
    const unsigned int* __restrict__ bbuf,
    const int* __restrict__ bst, const int* __restrict__ bcnt,
    unsigned short* __restrict__ mean_bf, int N)
{
    __shared__ unsigned int sb[AGG_CHUNK];    // sorted src, grouped by node
    __shared__ unsigned int tmp[AGG_CHUNK];   // raw chunk stage
    __shared__ int lc[NPB], lofs[NPB], lcur[NPB], dtot[NPB];

    int k     = blockIdx.x;
    int start = bst[k];
    int num   = bcnt[k];
    int tid   = threadIdx.x;
    int wave  = tid >> 6, lane = tid & 63;
    int g     = lane & 15, slot = lane >> 4;

    if (tid < NPB) dtot[tid] = 0;

    float acc[8][8];
    #pragma unroll
    for (int nl = 0; nl < 8; ++nl)
        #pragma unroll
        for (int j = 0; j < 8; ++j) acc[nl][j] = 0.0f;

    for (int c0 = 0; c0 < num; c0 += AGG_CHUNK) {
        int clen = num - c0; if (clen > AGG_CHUNK) clen = AGG_CHUNK;
        if (tid < NPB) lc[tid] = 0;
        __syncthreads();
        for (int i = tid; i < clen; i += 256) {
            unsigned int p = bbuf[start + c0 + i];
            tmp[i] = p;
            atomicAdd(&lc[p >> 26], 1);
        }
        __syncthreads();
        if (tid < NPB) {                       // lanes 0..31 of wave 0
            int v0 = lc[tid], v = v0;
            #pragma unroll
            for (int off = 1; off < 32; off <<= 1) {
                int t = __shfl_up(v, off, 32);
                if (tid >= off) v += t;
            }
            lofs[tid] = v - v0;
            lcur[tid] = 0;
            dtot[tid] += v0;
        }
        __syncthreads();
        for (int i = tid; i < clen; i += 256) {
            unsigned int p = tmp[i];
            int d = p >> 26;
            int pos = atomicAdd(&lcur[d], 1);
            sb[lofs[d] + pos] = p & 0x03FFFFFFu;
        }
        __syncthreads();
        #pragma unroll
        for (int nl = 0; nl < 8; ++nl) {
            int d    = wave * 8 + nl;
            int base = lofs[d];
            int len  = lc[d];
            int j    = slot;
            for (; j + 12 < len; j += 16) {    // 4 gathers in flight
                unsigned int s0 = sb[base + j];
                unsigned int s1 = sb[base + j + 4];
                unsigned int s2 = sb[base + j + 8];
                unsigned int s3 = sb[base + j + 12];
                uint2 w0 = x8[s0 * 16u + g];
                uint2 w1 = x8[s1 * 16u + g];
                uint2 w2 = x8[s2 * 16u + g];
                uint2 w3 = x8[s3 * 16u + g];
                ACC8(nl, w0); ACC8(nl, w1); ACC8(nl, w2); ACC8(nl, w3);
            }
            for (; j < len; j += 4) {
                uint2 w = x8[sb[base + j] * 16u + g];
                ACC8(nl, w);
            }
        }
        __syncthreads();   // protect lc/lofs/sb/tmp before next chunk
    }
    __syncthreads();       // dtot visible to all waves (also covers num==0)

    // reduce over the 4 slots and write mean rows (slot 0: 16 lanes x uint4)
    #pragma unroll
    for (int nl = 0; nl < 8; ++nl) {
        #pragma unroll
        for (int j = 0; j < 8; ++j) {
            acc[nl][j] += __shfl_xor(acc[nl][j], 16, 64);
            acc[nl][j] += __shfl_xor(acc[nl][j], 32, 64);
        }
        int d = wave * 8 + nl;
        int n = k * NPB + d;
        if (slot == 0 && n < N) {
            float inv = 1.0f / fmaxf((float)dtot[d], 1.0f);
            uint4 q;
            q.x = (unsigned int)f2bf(acc[nl][0] * inv) | ((unsigned int)f2bf(acc[nl][1] * inv) << 16);
            q.y = (unsigned int)f2bf(acc[nl][2] * inv) | ((unsigned int)f2bf(acc[nl][3] * inv) << 16);
            q.z = (unsigned int)f2bf(acc[nl][4] * inv) | ((unsigned int)f2bf(acc[nl][5] * inv) << 16);
            q.w = (unsigned int)f2bf(acc[nl][6] * inv) | ((unsigned int)f2bf(acc[nl][7] * inv) << 16);
            *(uint4*)(mean_bf + (long long)n * FDIM + g * 8) = q;
        }
    }
}

// ---------------------------------------------------------------------------
// MFMA GEMM: h = relu([mean|x]_bf16 @ Wc^T + bl) -> out + BN column stats.
// R12 PMC: latency-bound, Occupancy 15% — the 66KB LDS Wc tile capped
// residency at 2 blocks/CU. Fix: NO LDS staging. Wc is 64KB, shared by all
// blocks, L2-resident (re-read cost ~200MB/30TB/s ≈ 7us total). LDS now
// 1KB (reduction only) -> occupancy is VGPR-limited: ~4 blocks/CU =
// 16 waves/CU (2x). Grid 1024 = 4 blocks/CU, one balanced round.
// ---------------------------------------------------------------------------
__global__ __launch_bounds__(256) void mfma_gemm_kernel(
    const unsigned short* __restrict__ mean_bf,
    const unsigned short* __restrict__ x_bf,
    const void* __restrict__ xv,                // original x input
    const unsigned short* __restrict__ Wc_ws,   // [128][256] bf16 (L2-resident)
    const float* __restrict__ bl32,
    void* __restrict__ out,
    float* __restrict__ col_sum,                // [128] sums then [128] sqs
    const int* __restrict__ flags, int N)
{
    __shared__ float red[2 * FDIM];
    int f32out = flags[1];
    const unsigned short* x_src = f32out ? x_bf : (const unsigned short*)xv;

    int wave = threadIdx.x >> 6;
    int lane = threadIdx.x & 63;
    int m    = lane & 15;
    int quad = lane >> 4;

    float bias[8];
    #pragma unroll
    for (int c = 0; c < 8; ++c) bias[c] = bl32[c * 16 + m];

    float lsum[8] = {0,0,0,0,0,0,0,0};
    float lsq[8]  = {0,0,0,0,0,0,0,0};

    int nst = (N + 31) >> 5;
    for (int st = blockIdx.x * 4 + wave; st < nst; st += gridDim.x * 4) {
        int r0 = st * 32;
        v4f acc[8][2];
        #pragma unroll
        for (int c = 0; c < 8; ++c) {
            acc[c][0] = (v4f){0.f, 0.f, 0.f, 0.f};
            acc[c][1] = (v4f){0.f, 0.f, 0.f, 0.f};
        }
        int ra = r0 + m;      if (ra > N - 1) ra = N - 1;
        int rb = r0 + 16 + m; if (rb > N - 1) rb = N - 1;
        #pragma unroll
        for (int kk = 0; kk < 8; ++kk) {
            const unsigned short* base = (kk < 4) ? mean_bf : x_src;
            int koff = (kk & 3) * 32 + quad * 8;
            v8s a0 = *(const v8s*)(base + (long long)ra * FDIM + koff);
            v8s a1 = *(const v8s*)(base + (long long)rb * FDIM + koff);
            #pragma unroll
            for (int c = 0; c < 8; ++c) {
                v8s b = *(const v8s*)(Wc_ws + (c * 16 + m) * 256 + kk * 32 + quad * 8);
                acc[c][0] = __builtin_amdgcn_mfma_f32_16x16x32_bf16(a0, b, acc[c][0], 0, 0, 0);
                acc[c][1] = __builtin_amdgcn_mfma_f32_16x16x32_bf16(a1, b, acc[c][1], 0, 0, 0);
            }
        }
        #pragma unroll
        for (int c = 0; c < 8; ++c) {
            #pragma unroll
            for (int t = 0; t < 2; ++t) {
                #pragma unroll
                for (int reg = 0; reg < 4; ++reg) {
                    int row = r0 + t * 16 + quad * 4 + reg;
                    if (row < N) {
                        float v = acc[c][t][reg] + bias[c];
                        v = fmaxf(v, 0.0f);
                        if (f32out) ((float*)out)[(long long)row * FDIM + c * 16 + m] = v;
                        else ((unsigned short*)out)[(long long)row * FDIM + c * 16 + m] = f2bf(v);
                        lsum[c] += v;
                        lsq[c]  += v * v;
                    }
                }
            }
        }
    }

    red[threadIdx.x] = 0.0f;
    __syncthreads();
    #pragma unroll
    for (int c = 0; c < 8; ++c) {
        atomicAdd(&red[c * 16 + m],       lsum[c]);
        atomicAdd(&red[128 + c * 16 + m], lsq[c]);
    }
    __syncthreads();
    atomicAdd(&col_sum[threadIdx.x], red[threadIdx.x]);
}

// ---------------------------------------------------------------------------
// Fallback scatter + vector GEMM (only if ws too small / N too large).
// ---------------------------------------------------------------------------
__global__ __launch_bounds__(256) void scatter_kernel(
    const void* __restrict__ xv, const int* __restrict__ ei,
    float* __restrict__ agg, float* __restrict__ deg,
    const int* __restrict__ flags, int E, int N)
{
    long long idx = (long long)blockIdx.x * 256 + threadIdx.x;
    if (idx >= (long long)E * 16) return;
    int e = (int)(idx >> 4);
    int g = (int)(idx & 15);
    int is64 = flags[0];
    int src = edge_at(ei, e, is64);
    int dst = edge_at(ei, (long long)E + e, is64);
    if ((unsigned)src >= (unsigned)N || (unsigned)dst >= (unsigned)N) return;
    float v[8];
    if (flags[1]) {
        const float4* xr = (const float4*)xv;
        float4 a = xr[(long long)src * 32 + g * 2];
        float4 b = xr[(long long)src * 32 + g * 2 + 1];
        v[0] = a.x; v[1] = a.y; v[2] = a.z; v[3] = a.w;
        v[4] = b.x; v[5] = b.y; v[6] = b.z; v[7] = b.w;
    } else {
        uint4 p = ((const uint4*)xv)[(long long)src * 16 + g];
        v[0] = bf2f((unsigned short)(p.x & 0xFFFF)); v[1] = bf2f((unsigned short)(p.x >> 16));
        v[2] = bf2f((unsigned short)(p.y & 0xFFFF)); v[3] = bf2f((unsigned short)(p.y >> 16));
        v[4] = bf2f((unsigned short)(p.z & 0xFFFF)); v[5] = bf2f((unsigned short)(p.z >> 16));
        v[6] = bf2f((unsigned short)(p.w & 0xFFFF)); v[7] = bf2f((unsigned short)(p.w >> 16));
    }
    float* a = agg + (long long)dst * FDIM + g * 8;
    #pragma unroll
    for (int j = 0; j < 8; ++j) atomicAdd(a + j, v[j]);
    if (g == 0) atomicAdd(deg + dst, 1.0f);
}

__global__ __launch_bounds__(512) void gemm_kernel(
    const float* __restrict__ agg, const float* __restrict__ deg,
    const void* __restrict__ xv,
    const float* __restrict__ Wl32, const float* __restrict__ bl32,
    const float* __restrict__ Wr32,
    void* __restrict__ out,
    float* __restrict__ col_sum, float* __restrict__ col_sq,
    const int* __restrict__ flags, int nodes)
{
    __shared__ float mrow[4][FDIM];
    __shared__ float xrow[4][FDIM];
    int tid  = threadIdx.x;
    int slot = tid >> 7;
    int d    = tid & 127;
    int f32  = flags[1];
    float lsum = 0.0f, lsq = 0.0f;
    int ngroups = (nodes + 3) >> 2;
    for (int g = blockIdx.x; g < ngroups; g += gridDim.x) {
        int n = g * 4 + slot;
        __syncthreads();
        if (n < nodes) {
            float inv = 1.0f / fmaxf(deg[n], 1.0f);
            mrow[slot][d] = agg[(long long)n * FDIM + d] * inv;
            xrow[slot][d] = f32 ? ((const float*)xv)[(long long)n * FDIM + d]
                                : bf2f(((const unsigned short*)xv)[(long long)n * FDIM + d]);
        }
        __syncthreads();
        if (n < nodes) {
            float acc = bl32[d];
            const float4* wl4 = (const float4*)(Wl32 + d * FDIM);
            const float4* wr4 = (const float4*)(Wr32 + d * FDIM);
            const float* mr = mrow[slot];
            const float* xr = xrow[slot];
            #pragma unroll
            for (int c = 0; c < 32; ++c) {
                float4 wa = wl4[c];
                float4 wb = wr4[c];
                int k = c * 4;
                acc += wa.x * mr[k] + wa.y * mr[k + 1] + wa.z * mr[k + 2] + wa.w * mr[k + 3];
                acc += wb.x * xr[k] + wb.y * xr[k + 1] + wb.z * xr[k + 2] + wb.w * xr[k + 3];
            }
            acc = fmaxf(acc, 0.0f);
            if (f32) ((float*)out)[(long long)n * FDIM + d] = acc;
            else     ((unsigned short*)out)[(long long)n * FDIM + d] = f2bf(acc);
            lsum += acc;
            lsq  += acc * acc;
        }
    }
    __syncthreads();
    mrow[slot][d] = lsum;
    xrow[slot][d] = lsq;
    __syncthreads();
    if (slot == 0) {
        atomicAdd(&col_sum[d], mrow[0][d] + mrow[1][d] + mrow[2][d] + mrow[3][d]);
        atomicAdd(&col_sq[d],  xrow[0][d] + xrow[1][d] + xrow[2][d] + xrow[3][d]);
    }
}

// ---------------------------------------------------------------------------
// Final BN (fused prep): derive scale/shift per block in LDS from
// col_sum/col_sq + gamma/beta, then apply in-place on d_out.
// ---------------------------------------------------------------------------
__global__ __launch_bounds__(256) void ChemSageBlock_89206470738295_kernel(
    void* __restrict__ hv,
    const float* __restrict__ col_sum, const float* __restrict__ col_sq,
    const float* __restrict__ gm32, const float* __restrict__ bt32,
    const int* __restrict__ flags, int N, long long nd)
{
    __shared__ float s_scale[FDIM], s_shift[FDIM];
    int t = threadIdx.x;
    if (t < FDIM) {
        float invN = 1.0f / (float)N;
        float mu  = col_sum[t] * invN;
        float var = col_sq[t] * invN - mu * mu;
        float sc  = gm32[t] * rsqrtf(var + BN_EPS);
        s_scale[t] = sc;
        s_shift[t] = bt32[t] - mu * sc;
    }
    __syncthreads();
    long long idx = (long long)blockIdx.x * 256 + t;
    if (flags[1]) {
        long long tot = nd >> 2;
        if (idx >= tot) return;
        int d0 = (int)(idx & 31) * 4;
        float4 p = ((float4*)hv)[idx];
        p.x = p.x * s_scale[d0 + 0] + s_shift[d0 + 0];
        p.y = p.y * s_scale[d0 + 1] + s_shift[d0 + 1];
        p.z = p.z * s_scale[d0 + 2] + s_shift[d0 + 2];
        p.w = p.w * s_scale[d0 + 3] + s_shift[d0 + 3];
        ((float4*)hv)[idx] = p;
    } else {
        long long tot = nd >> 3;
        if (idx >= tot) return;
        int d0 = (int)(idx & 15) * 8;
        uint4 p = ((uint4*)hv)[idx];
        unsigned int q[4] = {p.x, p.y, p.z, p.w};
        #pragma unroll
        for (int j = 0; j < 4; ++j) {
            int dd = d0 + j * 2;
            float lo = bf2f((unsigned short)(q[j] & 0xFFFF));
            float hi = bf2f((unsigned short)(q[j] >> 16));
            lo = lo * s_scale[dd]     + s_shift[dd];
            hi = hi * s_scale[dd + 1] + s_shift[dd + 1];
            q[j] = (unsigned int)f2bf(lo) | ((unsigned int)f2bf(hi) << 16);
        }
        uint4 r; r.x = q[0]; r.y = q[1]; r.z = q[2]; r.w = q[3];
        ((uint4*)hv)[idx] = r;
    }
}

// ---------------------------------------------------------------------------
extern "C" __attribute__((visibility("default")))
void kernel_launch(void* const* d_in, const int* in_sizes, int n_in,
                   void* d_out, int out_size, void* d_ws, size_t ws_size,
                   hipStream_t stream)
{
    int N = 100000, E = 1600000;
    if (in_sizes) {
        if (in_sizes[0] > 0 && (in_sizes[0] % FDIM) == 0) N = in_sizes[0] / FDIM;
        if (in_sizes[1] > 0 && (in_sizes[1] % 2) == 0)    E = in_sizes[1] / 2;
    }
    const void* x  = d_in[0];
    const int*  ei = (const int*)d_in[1];
    const void* Wl = d_in[2];
    const void* bl = d_in[3];
    const void* Wr = d_in[4];
    const void* gm = d_in[5];
    const void* bt = d_in[6];

    int NB = (N + NPB - 1) / NPB;

    unsigned short* x_bf    = (unsigned short*)d_ws;
    unsigned short* mean_bf = x_bf + (size_t)N * FDIM;
    unsigned short* Wc      = mean_bf + (size_t)N * FDIM;
    float* Wl32    = (float*)(Wc + FDIM * 256);
    float* Wr32    = Wl32 + FDIM * FDIM;
    float* bl32    = Wr32 + FDIM * FDIM;
    float* gm32    = bl32 + FDIM;
    float* bt32    = gm32 + FDIM;
    float* scale   = bt32 + FDIM;
    float* shift   = scale + FDIM;
    float* col_sum = shift + FDIM;
    float* col_sq  = col_sum + FDIM;
    int*   flags   = (int*)(col_sq + FDIM);
    int*   bcnt    = flags + 16;
    int*   bcur    = bcnt + NB_CAP;
    int*   bst     = bcur + NB_CAP;
    unsigned int* bbuf = (unsigned int*)(bst + NB_CAP);
    size_t ws_need    = (size_t)((char*)(bbuf + E) - (char*)d_ws);
    (void)scale; (void)shift;

    // fp8 gather table lives in d_out (scratch until mfma_gemm writes it)
    uint2* x8 = (uint2*)d_out;
    int out_fits_x8 = (out_size >= N * FDIM);

    detect_convert_kernel<<<1, 1024, 0, stream>>>(
        (const unsigned int*)x, ei, Wl, bl, Wr, gm, bt,
        Wc, Wl32, Wr32, bl32, gm32, bt32, col_sum, bcnt, flags);

    long long nd = (long long)N * FDIM;

    if (ws_size >= ws_need && NB <= NB_CAP && out_fits_x8) {
        // Bucketed bin + fp8 register-accum aggregate + MFMA path
        long long n8 = nd >> 3;
        int cblocks = (int)((n8 + 255) / 256);
        convert_count_kernel<<<cblocks + 256, 256, 0, stream>>>(
            x, x_bf, x8, ei, bcnt, flags, n8, E, N, NB, cblocks);
        offset_kernel<<<(NB + 255) / 256, 256, 0, stream>>>(bcnt, bst, &flags[5], NB);
        bin_kernel<<<(E + BIN_CHUNK - 1) / BIN_CHUNK, 256, 0, stream>>>(
            ei, bst, bcur, bbuf, flags, E, N, NB);
        bucket_agg_kernel<<<NB, 256, 0, stream>>>(
            (const uint2*)x8, bbuf, bst, bcnt, mean_bf, N);
        mfma_gemm_kernel<<<1024, 256, 0, stream>>>(
            mean_bf, x_bf, x, Wc, bl32, d_out, col_sum, flags, N);
        ChemSageBlock_89206470738295_kernel<<<(int)((nd / 4 + 255) / 256), 256, 0, stream>>>(
            d_out, col_sum, col_sum + FDIM, gm32, bt32, flags, N, nd);
    } else {
        // Fallback: atomic scatter + vector GEMM. agg f32 aliases x_bf+mean_bf.
        float* agg = (float*)d_ws;
        float* deg = (float*)bcnt;                 // N floats into bcnt.. region
        zero_kernel<<<2048, 256, 0, stream>>>(agg, nd);
        zero_kernel<<<1, 256, 0, stream>>>(col_sum, 2 * FDIM);
        zero_kernel<<<(N + 255) / 256, 256, 0, stream>>>(deg, N);
        long long sc_threads = (long long)E * 16;
        scatter_kernel<<<(int)((sc_threads + 255) / 256), 256, 0, stream>>>(
            x, ei, agg, deg, flags, E, N);
        gemm_kernel<<<2048, 512, 0, stream>>>(agg, deg, x, Wl32, bl32, Wr32,
                                              d_out, col_sum, col_sq, flags, N);
        ChemSageBlock_89206470738295_kernel<<<(int)((nd / 4 + 255) / 256), 256, 0, stream>>>(
            d_out, col_sum, col_sq, gm32, bt32, flags, N, nd);
    }
}

// Round 15
// 298.360 us; speedup vs baseline: 1.1847x; 1.1847x over previous
//
#include <hip/hip_runtime.h>

#define FDIM 128
#define BN_EPS 1e-5f
#define LDS_STRIDE 264   // 256 + 8 bf16 pad for LDS b128 reads

#define NPB 32           // nodes per bucket (dst >> 5)
#define NB_CAP 4096      // supports N up to 131072 (< 2^26 so src packs in 26 bits)
#define BIN_CHUNK 4096   // edges per bin block (R7 form)
#define AGG_CHUNK 1024   // edges per aggregate chunk (LDS sort buffer)

typedef short v8s __attribute__((ext_vector_type(8)));
typedef float v4f __attribute__((ext_vector_type(4)));
typedef float floatx2 __attribute__((ext_vector_type(2)));

#if defined(__has_builtin)
#if __has_builtin(__builtin_amdgcn_cvt_pk_f32_fp8) && __has_builtin(__builtin_amdgcn_cvt_pk_fp8_f32)
#define HAVE_FP8_CVT 1
#endif
#endif
#ifndef HAVE_FP8_CVT
#define HAVE_FP8_CVT 0
#endif

__device__ __forceinline__ float bf2f(unsigned short u) {
    union { unsigned int i; float f; } v; v.i = ((unsigned int)u) << 16; return v.f;
}
__device__ __forceinline__ unsigned short f2bf(float f) {
    union { float f2; unsigned int i; } v; v.f2 = f;
    unsigned int r = v.i + 0x7FFFu + ((v.i >> 16) & 1u);  // RNE
    return (unsigned short)(r >> 16);
}

// ----- OCP e4m3fn encode/decode (manual fallback; HW cvt when available) ----
__device__ __forceinline__ unsigned char f2fp8(float f) {
    union { float f; unsigned u; } v; v.f = f;
    unsigned s = (v.u >> 24) & 0x80u;
    v.u &= 0x7FFFFFFFu;
    float a = v.f;
    if (!(a < 448.f)) a = 448.f;
    v.f = a;
    unsigned r;
    if (v.u < 0x3C800000u) {              // a < 2^-6 : subnormal (value = q * 2^-9)
        r = (unsigned)(int)(a * 512.0f + 0.5f);        // 0..8 (8 == min normal)
    } else {
        unsigned t = v.u + 0x7FFFFu + ((v.u >> 20) & 1u);  // RNE to 3-bit mantissa
        int e = (int)(t >> 23) - 120;
        unsigned m = (t >> 20) & 7u;
        if (e > 15) { e = 15; m = 6; }    // clamp to 448
        r = ((unsigned)e << 3) | m;
    }
    return (unsigned char)(r | s);
}
__device__ __forceinline__ float fp82f(unsigned int u) {
    u &= 0xFFu;
    unsigned em = u & 0x7Fu;
    union { unsigned u; float f; } v;
    v.u = ((u & 0x80u) << 24) | ((em + 960u) << 20);
    float sub = (float)(int)em * 0.001953125f;         // em * 2^-9
    if (u & 0x80u) sub = -sub;
    return (em < 8u) ? sub : v.f;
}
__device__ __forceinline__ unsigned int pack_fp8x4(float f0, float f1, float f2, float f3) {
#if HAVE_FP8_CVT
    unsigned int r = (unsigned int)__builtin_amdgcn_cvt_pk_fp8_f32(f0, f1, 0, false);
    r = (unsigned int)__builtin_amdgcn_cvt_pk_fp8_f32(f2, f3, (int)r, true);
    return r;
#else
    return (unsigned int)f2fp8(f0) | ((unsigned int)f2fp8(f1) << 8) |
           ((unsigned int)f2fp8(f2) << 16) | ((unsigned int)f2fp8(f3) << 24);
#endif
}

// ---------------------------------------------------------------------------
// Detect dtypes (wave-parallel); build Wc (bf16 [128][256]), f32 params;
// zero cursors, col_sum/col_sq and bcnt/bcur.
// flags[0]=ei_is_int64, flags[1]=floats_are_f32, flags[4]/[5]=alloc cursors.
// ---------------------------------------------------------------------------
__global__ __launch_bounds__(1024) void detect_convert_kernel(
    const unsigned int* __restrict__ xw, const int* __restrict__ ei,
    const void* __restrict__ Wl, const void* __restrict__ bl,
    const void* __restrict__ Wr, const void* __restrict__ gm,
    const void* __restrict__ bt,
    unsigned short* __restrict__ Wc,
    float* __restrict__ Wl32, float* __restrict__ Wr32,
    float* __restrict__ bl32, float* __restrict__ gm32, float* __restrict__ bt32,
    float* __restrict__ col_sum,        // 2*FDIM floats
    int* __restrict__ bcnt,             // 2*NB_CAP ints (bcnt+bcur contiguous)
    int* __restrict__ flags)
{
    __shared__ int s_any, s_cnt, s_f32;
    int tid = threadIdx.x;
    if (tid == 0) { s_any = 0; s_cnt = 0; }
    __syncthreads();
    if (tid < 128) {
        atomicOr(&s_any, ei[2 * tid + 1]);
        unsigned short h = (unsigned short)(xw[tid] & 0xFFFFu);
        int e = (h >> 7) & 0xFF;
        atomicAdd(&s_cnt, (h == 0 || (e >= 116 && e <= 133)) ? 1 : 0);
    }
    __syncthreads();
    if (tid == 0) {
        flags[0] = (s_any == 0) ? 1 : 0;
        int f32 = (s_cnt < 64) ? 1 : 0;
        flags[1] = f32;
        s_f32 = f32;
        flags[4] = 0;
        flags[5] = 0;
    }
    for (int i = tid; i < 2 * NB_CAP; i += blockDim.x) bcnt[i] = 0;
    if (tid < 2 * FDIM) col_sum[tid] = 0.0f;
    __syncthreads();
    int f32 = s_f32;
    for (int i = tid; i < FDIM * FDIM; i += blockDim.x) {
        int d = i >> 7, k = i & 127;
        float wl = f32 ? ((const float*)Wl)[i] : bf2f(((const unsigned short*)Wl)[i]);
        float wr = f32 ? ((const float*)Wr)[i] : bf2f(((const unsigned short*)Wr)[i]);
        Wl32[i] = wl;
        Wr32[i] = wr;
        Wc[d * 256 + k]       = f2bf(wl);
        Wc[d * 256 + 128 + k] = f2bf(wr);
    }
    if (tid < FDIM) {
        bl32[tid] = f32 ? ((const float*)bl)[tid] : bf2f(((const unsigned short*)bl)[tid]);
        gm32[tid] = f32 ? ((const float*)gm)[tid] : bf2f(((const unsigned short*)gm)[tid]);
        bt32[tid] = f32 ? ((const float*)bt)[tid] : bf2f(((const unsigned short*)bt)[tid]);
    }
}

__device__ __forceinline__ int edge_at(const int* ei, long long pos, int is64) {
    return is64 ? ei[2 * pos] : ei[pos];
}

// ---------------------------------------------------------------------------
// Fused: x -> bf16 copy (f32 input only; bf16 input read directly by gemm)
// + fp8 gather-table (blocks [0, cblocks)) + bucket histogram (blocks
// [cblocks, cblocks+256)). x8 lives in d_out (scratch until final BN).
// ---------------------------------------------------------------------------
__global__ __launch_bounds__(256) void convert_count_kernel(
    const void* __restrict__ xv, unsigned short* __restrict__ x_bf,
    uint2* __restrict__ x8,
    const int* __restrict__ ei, int* __restrict__ bcnt,
    const int* __restrict__ flags, long long n8, int E, int N, int NB,
    int cblocks)
{
    __shared__ int lcnt[NB_CAP];
    if ((int)blockIdx.x < cblocks) {
        long long i = (long long)blockIdx.x * 256 + threadIdx.x;
        if (i >= n8) return;
        float f0, f1, f2, f3, f4, f5, f6, f7;
        if (flags[1]) {
            const float4* xf = (const float4*)xv;
            float4 a = xf[i * 2], b = xf[i * 2 + 1];
            f0 = a.x; f1 = a.y; f2 = a.z; f3 = a.w;
            f4 = b.x; f5 = b.y; f6 = b.z; f7 = b.w;
            uint4 p;
            p.x = (unsigned int)f2bf(f0) | ((unsigned int)f2bf(f1) << 16);
            p.y = (unsigned int)f2bf(f2) | ((unsigned int)f2bf(f3) << 16);
            p.z = (unsigned int)f2bf(f4) | ((unsigned int)f2bf(f5) << 16);
            p.w = (unsigned int)f2bf(f6) | ((unsigned int)f2bf(f7) << 16);
            ((uint4*)x_bf)[i] = p;
        } else {
            uint4 p = ((const uint4*)xv)[i];
            // no x_bf store: gemm reads original x directly (same layout)
            f0 = bf2f((unsigned short)(p.x & 0xFFFF)); f1 = bf2f((unsigned short)(p.x >> 16));
            f2 = bf2f((unsigned short)(p.y & 0xFFFF)); f3 = bf2f((unsigned short)(p.y >> 16));
            f4 = bf2f((unsigned short)(p.z & 0xFFFF)); f5 = bf2f((unsigned short)(p.z >> 16));
            f6 = bf2f((unsigned short)(p.w & 0xFFFF)); f7 = bf2f((unsigned short)(p.w >> 16));
        }
        uint2 q;
        q.x = pack_fp8x4(f0, f1, f2, f3);
        q.y = pack_fp8x4(f4, f5, f6, f7);
        x8[i] = q;
    } else {
        int cb = (int)blockIdx.x - cblocks;     // 0..255
        for (int i = threadIdx.x; i < NB; i += 256) lcnt[i] = 0;
        __syncthreads();
        int is64 = flags[0];
        for (long long e = (long long)cb * 256 + threadIdx.x; e < E;
             e += 256LL * 256) {
            int src = edge_at(ei, e, is64);
            int dst = edge_at(ei, (long long)E + e, is64);
            if ((unsigned)src >= (unsigned)N || (unsigned)dst >= (unsigned)N) continue;
            atomicAdd(&lcnt[dst >> 5], 1);
        }
        __syncthreads();
        for (int i = threadIdx.x; i < NB; i += 256) {
            int c = lcnt[i];
            if (c) atomicAdd(&bcnt[i], c);
        }
    }
}

// ---------------------------------------------------------------------------
__global__ __launch_bounds__(256) void zero_kernel(float* __restrict__ z, long long n)
{
    long long i = (long long)blockIdx.x * 256 + threadIdx.x;
    long long stride = (long long)gridDim.x * 256;
    for (; i < n; i += stride) z[i] = 0.0f;
}

// ---------------------------------------------------------------------------
// Bucket phase 2: order-free range allocation over NB buckets (wave scan +
// one atomic per wave). Disjoint ranges; global order irrelevant.
// ---------------------------------------------------------------------------
__global__ __launch_bounds__(256) void offset_kernel(
    const int* __restrict__ cnt, int* __restrict__ row_start,
    int* __restrict__ counter, int N)
{
    int i = blockIdx.x * 256 + threadIdx.x;
    int lane = threadIdx.x & 63;
    int v0 = (i < N) ? cnt[i] : 0;
    int v = v0;
    #pragma unroll
    for (int off = 1; off < 64; off <<= 1) {
        int t = __shfl_up(v, off, 64);
        if (lane >= off) v += t;
    }
    int total = __shfl(v, 63, 64);
    int base = 0;
    if (lane == 0) base = atomicAdd(counter, total);
    base = __shfl(base, 0, 64);
    if (i < N) row_start[i] = base + v - v0;
}

// ---------------------------------------------------------------------------
// Bucket phase 3 (R7 form — measured best): chunk staged in LDS (src/dst)
// so ei is read ONCE; count -> reserve one range per (block,bucket) ->
// scatter packed (dst_local<<26)|src from LDS.
// ---------------------------------------------------------------------------
__global__ __launch_bounds__(256) void bin_kernel(
    const int* __restrict__ ei, const int* __restrict__ bst,
    int* __restrict__ bcur, unsigned int* __restrict__ bbuf,
    const int* __restrict__ flags, int E, int N, int NB)
{
    __shared__ int lcnt[NB_CAP];
    __shared__ int lbase[NB_CAP];
    __shared__ int ssrc[BIN_CHUNK];
    __shared__ int sdst[BIN_CHUNK];
    for (int i = threadIdx.x; i < NB; i += 256) lcnt[i] = 0;
    __syncthreads();
    long long e0 = (long long)blockIdx.x * BIN_CHUNK;
    int is64 = flags[0];
    for (int j = 0; j < BIN_CHUNK / 256; ++j) {
        int idx = j * 256 + threadIdx.x;
        long long e = e0 + idx;
        int d = -1, s = 0;
        if (e < E) {
            s = edge_at(ei, e, is64);
            int dd = edge_at(ei, (long long)E + e, is64);
            if ((unsigned)s < (unsigned)N && (unsigned)dd < (unsigned)N) d = dd;
        }
        ssrc[idx] = s;
        sdst[idx] = d;
        if (d >= 0) atomicAdd(&lcnt[d >> 5], 1);
    }
    __syncthreads();
    for (int i = threadIdx.x; i < NB; i += 256) {
        int c = lcnt[i];
        lbase[i] = c ? atomicAdd(&bcur[i], c) : 0;
    }
    __syncthreads();
    for (int j = 0; j < BIN_CHUNK / 256; ++j) {
        int idx = j * 256 + threadIdx.x;
        int d = sdst[idx];
        if (d < 0) continue;
        int b = d >> 5;
        int pos = atomicAdd(&lbase[b], 1);
        bbuf[bst[b] + pos] = ((unsigned int)(d & 31) << 26) | (unsigned int)ssrc[idx];
    }
}

#if HAVE_FP8_CVT
#define ACC8(nl, w) do { \
    floatx2 _a = __builtin_amdgcn_cvt_pk_f32_fp8((int)(w).x, false); \
    floatx2 _b = __builtin_amdgcn_cvt_pk_f32_fp8((int)(w).x, true);  \
    floatx2 _c = __builtin_amdgcn_cvt_pk_f32_fp8((int)(w).y, false); \
    floatx2 _d = __builtin_amdgcn_cvt_pk_f32_fp8((int)(w).y, true);  \
    acc[nl][0] += _a.x; acc[nl][1] += _a.y; acc[nl][2] += _b.x; acc[nl][3] += _b.y; \
    acc[nl][4] += _c.x; acc[nl][5] += _c.y; acc[nl][6] += _d.x; acc[nl][7] += _d.y; \
} while (0)
#else
#define ACC8(nl, w) do { \
    acc[nl][0] += fp82f((w).x);       acc[nl][1] += fp82f((w).x >> 8);  \
    acc[nl][2] += fp82f((w).x >> 16); acc[nl][3] += fp82f((w).x >> 24); \
    acc[nl][4] += fp82f((w).y);       acc[nl][5] += fp82f((w).y >> 8);  \
    acc[nl][6] += fp82f((w).y >> 16); acc[nl][7] += fp82f((w).y >> 24); \
} while (0)
#endif

// ---------------------------------------------------------------------------
// Bucket phase 4 (single dispatch): one block (256 thr, 4 waves) per
// 32-node bucket, REGISTER accumulation; gathers 128B fp8 rows. At the
// random-access fabric floor (R7 measured).
// ---------------------------------------------------------------------------
__global__ __launch_bounds__(256) void bucket_agg_kernel(
    const uint2* __restrict__ x8,             // fp8 table [N][16] uint2
    const unsigned int* __restrict__ bbuf,
    const int* __restrict__ bst, const int* __restrict__ bcnt,
    unsigned short* __restrict__ mean_bf, int N)
{
    __shared__ unsigned int sb[AGG_CHUNK];    // sorted src, grouped by node
    __shared__ unsigned int tmp[AGG_CHUNK];   // raw chunk stage
    __shared__ int lc[NPB], lofs[NPB], lcur[NPB], dtot[NPB];

    int k     = blockIdx.x;
    int start = bst[k];
    int num   = bcnt[k];
    int tid   = threadIdx.x;
    int wave  = tid >> 6, lane = tid & 63;
    int g     = lane & 15, slot = lane >> 4;

    if (tid < NPB) dtot[tid] = 0;

    float acc[8][8];
    #pragma unroll
    for (int nl = 0; nl < 8; ++nl)
        #pragma unroll
        for (int j = 0; j < 8; ++j) acc[nl][j] = 0.0f;

    for (int c0 = 0; c0 < num; c0 += AGG_CHUNK) {
        int clen = num - c0; if (clen > AGG_CHUNK) clen = AGG_CHUNK;
        if (tid < NPB) lc[tid] = 0;
        __syncthreads();
        for (int i = tid; i < clen; i += 256) {
            unsigned int p = bbuf[start + c0 + i];
            tmp[i] = p;
            atomicAdd(&lc[p >> 26], 1);
        }
        __syncthreads();
        if (tid < NPB) {                       // lanes 0..31 of wave 0
            int v0 = lc[tid], v = v0;
            #pragma unroll
            for (int off = 1; off < 32; off <<= 1) {
                int t = __shfl_up(v, off, 32);
                if (tid >= off) v += t;
            }
            lofs[tid] = v - v0;
            lcur[tid] = 0;
            dtot[tid] += v0;
        }
        __syncthreads();
        for (int i = tid; i < clen; i += 256) {
            unsigned int p = tmp[i];
            int d = p >> 26;
            int pos = atomicAdd(&lcur[d], 1);
            sb[lofs[d] + pos] = p & 0x03FFFFFFu;
        }
        __syncthreads();
        #pragma unroll
        for (int nl = 0; nl < 8; ++nl) {
            int d    = wave * 8 + nl;
            int base = lofs[d];
            int len  = lc[d];
            int j    = slot;
            for (; j + 12 < len; j += 16) {    // 4 gathers in flight
                unsigned int s0 = sb[base + j];
                unsigned int s1 = sb[base + j + 4];
                unsigned int s2 = sb[base + j + 8];
                unsigned int s3 = sb[base + j + 12];
                uint2 w0 = x8[s0 * 16u + g];
                uint2 w1 = x8[s1 * 16u + g];
                uint2 w2 = x8[s2 * 16u + g];
                uint2 w3 = x8[s3 * 16u + g];
                ACC8(nl, w0); ACC8(nl, w1); ACC8(nl, w2); ACC8(nl, w3);
            }
            for (; j < len; j += 4) {
                uint2 w = x8[sb[base + j] * 16u + g];
                ACC8(nl, w);
            }
        }
        __syncthreads();   // protect lc/lofs/sb/tmp before next chunk
    }
    __syncthreads();       // dtot visible to all waves (also covers num==0)

    // reduce over the 4 slots and write mean rows (slot 0: 16 lanes x uint4)
    #pragma unroll
    for (int nl = 0; nl < 8; ++nl) {
        #pragma unroll
        for (int j = 0; j < 8; ++j) {
            acc[nl][j] += __shfl_xor(acc[nl][j], 16, 64);
            acc[nl][j] += __shfl_xor(acc[nl][j], 32, 64);
        }
        int d = wave * 8 + nl;
        int n = k * NPB + d;
        if (slot == 0 && n < N) {
            float inv = 1.0f / fmaxf((float)dtot[d], 1.0f);
            uint4 q;
            q.x = (unsigned int)f2bf(acc[nl][0] * inv) | ((unsigned int)f2bf(acc[nl][1] * inv) << 16);
            q.y = (unsigned int)f2bf(acc[nl][2] * inv) | ((unsigned int)f2bf(acc[nl][3] * inv) << 16);
            q.z = (unsigned int)f2bf(acc[nl][4] * inv) | ((unsigned int)f2bf(acc[nl][5] * inv) << 16);
            q.w = (unsigned int)f2bf(acc[nl][6] * inv) | ((unsigned int)f2bf(acc[nl][7] * inv) << 16);
            *(uint4*)(mean_bf + (long long)n * FDIM + g * 8) = q;
        }
    }
}

// ---------------------------------------------------------------------------
// MFMA GEMM (R11/R12 measured-best form): h = relu([mean|x]_bf16 @ Wc^T+bl)
// -> out (f32/bf16 per flag) + BN column stats. LDS-staged Wc (66KB), 256
// threads, grid 512 (2 blocks/CU, one balanced round). R13's 512-thread
// variant was neutral; R14's no-LDS variant exploded VGPRs (108->232,
// occupancy 15%->9.6%, 46->118us) — global B-frags force the compiler to
// hold 64 in-flight fragments in registers. Do not remove LDS staging.
// ---------------------------------------------------------------------------
__global__ __launch_bounds__(256) void mfma_gemm_kernel(
    const unsigned short* __restrict__ mean_bf,
    const unsigned short* __restrict__ x_bf,
    const void* __restrict__ xv,                // original x input
    const unsigned short* __restrict__ Wc_ws,   // [128][256] bf16
    const float* __restrict__ bl32,
    void* __restrict__ out,
    float* __restrict__ col_sum,                // [128] sums then [128] sqs
    const int* __restrict__ flags, int N)
{
    __shared__ unsigned short Wc[FDIM * LDS_STRIDE];
    int f32out = flags[1];
    const unsigned short* x_src = f32out ? x_bf : (const unsigned short*)xv;

    for (int i = threadIdx.x; i < FDIM * 32; i += 256) {
        int row = i >> 5;
        int g8  = i & 31;
        *(uint4*)(Wc + row * LDS_STRIDE + g8 * 8) =
            *(const uint4*)(Wc_ws + row * 256 + g8 * 8);
    }
    __syncthreads();

    int wave = threadIdx.x >> 6;
    int lane = threadIdx.x & 63;
    int m    = lane & 15;
    int quad = lane >> 4;

    float bias[8];
    #pragma unroll
    for (int c = 0; c < 8; ++c) bias[c] = bl32[c * 16 + m];

    float lsum[8] = {0,0,0,0,0,0,0,0};
    float lsq[8]  = {0,0,0,0,0,0,0,0};

    int nst = (N + 31) >> 5;
    for (int st = blockIdx.x * 4 + wave; st < nst; st += gridDim.x * 4) {
        int r0 = st * 32;
        v4f acc[8][2];
        #pragma unroll
        for (int c = 0; c < 8; ++c) {
            acc[c][0] = (v4f){0.f, 0.f, 0.f, 0.f};
            acc[c][1] = (v4f){0.f, 0.f, 0.f, 0.f};
        }
        int ra = r0 + m;      if (ra > N - 1) ra = N - 1;
        int rb = r0 + 16 + m; if (rb > N - 1) rb = N - 1;
        #pragma unroll
        for (int kk = 0; kk < 8; ++kk) {
            const unsigned short* base = (kk < 4) ? mean_bf : x_src;
            int koff = (kk & 3) * 32 + quad * 8;
            v8s a0 = *(const v8s*)(base + (long long)ra * FDIM + koff);
            v8s a1 = *(const v8s*)(base + (long long)rb * FDIM + koff);
            #pragma unroll
            for (int c = 0; c < 8; ++c) {
                v8s b = *(const v8s*)(Wc + (c * 16 + m) * LDS_STRIDE + kk * 32 + quad * 8);
                acc[c][0] = __builtin_amdgcn_mfma_f32_16x16x32_bf16(a0, b, acc[c][0], 0, 0, 0);
                acc[c][1] = __builtin_amdgcn_mfma_f32_16x16x32_bf16(a1, b, acc[c][1], 0, 0, 0);
            }
        }
        #pragma unroll
        for (int c = 0; c < 8; ++c) {
            #pragma unroll
            for (int t = 0; t < 2; ++t) {
                #pragma unroll
                for (int reg = 0; reg < 4; ++reg) {
                    int row = r0 + t * 16 + quad * 4 + reg;
                    if (row < N) {
                        float v = acc[c][t][reg] + bias[c];
                        v = fmaxf(v, 0.0f);
                        if (f32out) ((float*)out)[(long long)row * FDIM + c * 16 + m] = v;
                        else ((unsigned short*)out)[(long long)row * FDIM + c * 16 + m] = f2bf(v);
                        lsum[c] += v;
                        lsq[c]  += v * v;
                    }
                }
            }
        }
    }

    __syncthreads();
    float* red = (float*)Wc;
    red[threadIdx.x] = 0.0f;
    __syncthreads();
    #pragma unroll
    for (int c = 0; c < 8; ++c) {
        atomicAdd(&red[c * 16 + m],       lsum[c]);
        atomicAdd(&red[128 + c * 16 + m], lsq[c]);
    }
    __syncthreads();
    atomicAdd(&col_sum[threadIdx.x], red[threadIdx.x]);
}

// ---------------------------------------------------------------------------
// Fallback scatter + vector GEMM (only if ws too small / N too large).
// ---------------------------------------------------------------------------
__global__ __launch_bounds__(256) void scatter_kernel(
    const void* __restrict__ xv, const int* __restrict__ ei,
    float* __restrict__ agg, float* __restrict__ deg,
    const int* __restrict__ flags, int E, int N)
{
    long long idx = (long long)blockIdx.x * 256 + threadIdx.x;
    if (idx >= (long long)E * 16) return;
    int e = (int)(idx >> 4);
    int g = (int)(idx & 15);
    int is64 = flags[0];
    int src = edge_at(ei, e, is64);
    int dst = edge_at(ei, (long long)E + e, is64);
    if ((unsigned)src >= (unsigned)N || (unsigned)dst >= (unsigned)N) return;
    float v[8];
    if (flags[1]) {
        const float4* xr = (const float4*)xv;
        float4 a = xr[(long long)src * 32 + g * 2];
        float4 b = xr[(long long)src * 32 + g * 2 + 1];
        v[0] = a.x; v[1] = a.y; v[2] = a.z; v[3] = a.w;
        v[4] = b.x; v[5] = b.y; v[6] = b.z; v[7] = b.w;
    } else {
        uint4 p = ((const uint4*)xv)[(long long)src * 16 + g];
        v[0] = bf2f((unsigned short)(p.x & 0xFFFF)); v[1] = bf2f((unsigned short)(p.x >> 16));
        v[2] = bf2f((unsigned short)(p.y & 0xFFFF)); v[3] = bf2f((unsigned short)(p.y >> 16));
        v[4] = bf2f((unsigned short)(p.z & 0xFFFF)); v[5] = bf2f((unsigned short)(p.z >> 16));
        v[6] = bf2f((unsigned short)(p.w & 0xFFFF)); v[7] = bf2f((unsigned short)(p.w >> 16));
    }
    float* a = agg + (long long)dst * FDIM + g * 8;
    #pragma unroll
    for (int j = 0; j < 8; ++j) atomicAdd(a + j, v[j]);
    if (g == 0) atomicAdd(deg + dst, 1.0f);
}

__global__ __launch_bounds__(512) void gemm_kernel(
    const float* __restrict__ agg, const float* __restrict__ deg,
    const void* __restrict__ xv,
    const float* __restrict__ Wl32, const float* __restrict__ bl32,
    const float* __restrict__ Wr32,
    void* __restrict__ out,
    float* __restrict__ col_sum, float* __restrict__ col_sq,
    const int* __restrict__ flags, int nodes)
{
    __shared__ float mrow[4][FDIM];
    __shared__ float xrow[4][FDIM];
    int tid  = threadIdx.x;
    int slot = tid >> 7;
    int d    = tid & 127;
    int f32  = flags[1];
    float lsum = 0.0f, lsq = 0.0f;
    int ngroups = (nodes + 3) >> 2;
    for (int g = blockIdx.x; g < ngroups; g += gridDim.x) {
        int n = g * 4 + slot;
        __syncthreads();
        if (n < nodes) {
            float inv = 1.0f / fmaxf(deg[n], 1.0f);
            mrow[slot][d] = agg[(long long)n * FDIM + d] * inv;
            xrow[slot][d] = f32 ? ((const float*)xv)[(long long)n * FDIM + d]
                                : bf2f(((const unsigned short*)xv)[(long long)n * FDIM + d]);
        }
        __syncthreads();
        if (n < nodes) {
            float acc = bl32[d];
            const float4* wl4 = (const float4*)(Wl32 + d * FDIM);
            const float4* wr4 = (const float4*)(Wr32 + d * FDIM);
            const float* mr = mrow[slot];
            const float* xr = xrow[slot];
            #pragma unroll
            for (int c = 0; c < 32; ++c) {
                float4 wa = wl4[c];
                float4 wb = wr4[c];
                int k = c * 4;
                acc += wa.x * mr[k] + wa.y * mr[k + 1] + wa.z * mr[k + 2] + wa.w * mr[k + 3];
                acc += wb.x * xr[k] + wb.y * xr[k + 1] + wb.z * xr[k + 2] + wb.w * xr[k + 3];
            }
            acc = fmaxf(acc, 0.0f);
            if (f32) ((float*)out)[(long long)n * FDIM + d] = acc;
            else     ((unsigned short*)out)[(long long)n * FDIM + d] = f2bf(acc);
            lsum += acc;
            lsq  += acc * acc;
        }
    }
    __syncthreads();
    mrow[slot][d] = lsum;
    xrow[slot][d] = lsq;
    __syncthreads();
    if (slot == 0) {
        atomicAdd(&col_sum[d], mrow[0][d] + mrow[1][d] + mrow[2][d] + mrow[3][d]);
        atomicAdd(&col_sq[d],  xrow[0][d] + xrow[1][d] + xrow[2][d] + xrow[3][d]);
    }
}

// ---------------------------------------------------------------------------
// Final BN (fused prep): derive scale/shift per block in LDS from
// col_sum/col_sq + gamma/beta, then apply in-place on d_out.
// ---------------------------------------------------------------------------
__global__ __launch_bounds__(256) void ChemSageBlock_89206470738295_kernel(
    void* __restrict__ hv,
    const float* __restrict__ col_sum, const float* __restrict__ col_sq,
    const float* __restrict__ gm32, const float* __restrict__ bt32,
    const int* __restrict__ flags, int N, long long nd)
{
    __shared__ float s_scale[FDIM], s_shift[FDIM];
    int t = threadIdx.x;
    if (t < FDIM) {
        float invN = 1.0f / (float)N;
        float mu  = col_sum[t] * invN;
        float var = col_sq[t] * invN - mu * mu;
        float sc  = gm32[t] * rsqrtf(var + BN_EPS);
        s_scale[t] = sc;
        s_shift[t] = bt32[t] - mu * sc;
    }
    __syncthreads();
    long long idx = (long long)blockIdx.x * 256 + t;
    if (flags[1]) {
        long long tot = nd >> 2;
        if (idx >= tot) return;
        int d0 = (int)(idx & 31) * 4;
        float4 p = ((float4*)hv)[idx];
        p.x = p.x * s_scale[d0 + 0] + s_shift[d0 + 0];
        p.y = p.y * s_scale[d0 + 1] + s_shift[d0 + 1];
        p.z = p.z * s_scale[d0 + 2] + s_shift[d0 + 2];
        p.w = p.w * s_scale[d0 + 3] + s_shift[d0 + 3];
        ((float4*)hv)[idx] = p;
    } else {
        long long tot = nd >> 3;
        if (idx >= tot) return;
        int d0 = (int)(idx & 15) * 8;
        uint4 p = ((uint4*)hv)[idx];
        unsigned int q[4] = {p.x, p.y, p.z, p.w};
        #pragma unroll
        for (int j = 0; j < 4; ++j) {
            int dd = d0 + j * 2;
            float lo = bf2f((unsigned short)(q[j] & 0xFFFF));
            float hi = bf2f((unsigned short)(q[j] >> 16));
            lo = lo * s_scale[dd]     + s_shift[dd];
            hi = hi * s_scale[dd + 1] + s_shift[dd + 1];
            q[j] = (unsigned int)f2bf(lo) | ((unsigned int)f2bf(hi) << 16);
        }
        uint4 r; r.x = q[0]; r.y = q[1]; r.z = q[2]; r.w = q[3];
        ((uint4*)hv)[idx] = r;
    }
}

// ---------------------------------------------------------------------------
extern "C" __attribute__((visibility("default")))
void kernel_launch(void* const* d_in, const int* in_sizes, int n_in,
                   void* d_out, int out_size, void* d_ws, size_t ws_size,
                   hipStream_t stream)
{
    int N = 100000, E = 1600000;
    if (in_sizes) {
        if (in_sizes[0] > 0 && (in_sizes[0] % FDIM) == 0) N = in_sizes[0] / FDIM;
        if (in_sizes[1] > 0 && (in_sizes[1] % 2) == 0)    E = in_sizes[1] / 2;
    }
    const void* x  = d_in[0];
    const int*  ei = (const int*)d_in[1];
    const void* Wl = d_in[2];
    const void* bl = d_in[3];
    const void* Wr = d_in[4];
    const void* gm = d_in[5];
    const void* bt = d_in[6];

    int NB = (N + NPB - 1) / NPB;

    unsigned short* x_bf    = (unsigned short*)d_ws;
    unsigned short* mean_bf = x_bf + (size_t)N * FDIM;
    unsigned short* Wc      = mean_bf + (size_t)N * FDIM;
    float* Wl32    = (float*)(Wc + FDIM * 256);
    float* Wr32    = Wl32 + FDIM * FDIM;
    float* bl32    = Wr32 + FDIM * FDIM;
    float* gm32    = bl32 + FDIM;
    float* bt32    = gm32 + FDIM;
    float* scale   = bt32 + FDIM;
    float* shift   = scale + FDIM;
    float* col_sum = shift + FDIM;
    float* col_sq  = col_sum + FDIM;
    int*   flags   = (int*)(col_sq + FDIM);
    int*   bcnt    = flags + 16;
    int*   bcur    = bcnt + NB_CAP;
    int*   bst     = bcur + NB_CAP;
    unsigned int* bbuf = (unsigned int*)(bst + NB_CAP);
    size_t ws_need    = (size_t)((char*)(bbuf + E) - (char*)d_ws);
    (void)scale; (void)shift;

    // fp8 gather table lives in d_out (scratch until mfma_gemm writes it)
    uint2* x8 = (uint2*)d_out;
    int out_fits_x8 = (out_size >= N * FDIM);

    detect_convert_kernel<<<1, 1024, 0, stream>>>(
        (const unsigned int*)x, ei, Wl, bl, Wr, gm, bt,
        Wc, Wl32, Wr32, bl32, gm32, bt32, col_sum, bcnt, flags);

    long long nd = (long long)N * FDIM;

    if (ws_size >= ws_need && NB <= NB_CAP && out_fits_x8) {
        // Bucketed bin + fp8 register-accum aggregate + MFMA path
        long long n8 = nd >> 3;
        int cblocks = (int)((n8 + 255) / 256);
        convert_count_kernel<<<cblocks + 256, 256, 0, stream>>>(
            x, x_bf, x8, ei, bcnt, flags, n8, E, N, NB, cblocks);
        offset_kernel<<<(NB + 255) / 256, 256, 0, stream>>>(bcnt, bst, &flags[5], NB);
        bin_kernel<<<(E + BIN_CHUNK - 1) / BIN_CHUNK, 256, 0, stream>>>(
            ei, bst, bcur, bbuf, flags, E, N, NB);
        bucket_agg_kernel<<<NB, 256, 0, stream>>>(
            (const uint2*)x8, bbuf, bst, bcnt, mean_bf, N);
        mfma_gemm_kernel<<<512, 256, 0, stream>>>(
            mean_bf, x_bf, x, Wc, bl32, d_out, col_sum, flags, N);
        ChemSageBlock_89206470738295_kernel<<<(int)((nd / 4 + 255) / 256), 256, 0, stream>>>(
            d_out, col_sum, col_sum + FDIM, gm32, bt32, flags, N, nd);
    } else {
        // Fallback: atomic scatter + vector GEMM. agg f32 aliases x_bf+mean_bf.
        float* agg = (float*)d_ws;
        float* deg = (float*)bcnt;                 // N floats into bcnt.. region
        zero_kernel<<<2048, 256, 0, stream>>>(agg, nd);
        zero_kernel<<<1, 256, 0, stream>>>(col_sum, 2 * FDIM);
        zero_kernel<<<(N + 255) / 256, 256, 0, stream>>>(deg, N);
        long long sc_threads = (long long)E * 16;
        scatter_kernel<<<(int)((sc_threads + 255) / 256), 256, 0, stream>>>(
            x, ei, agg, deg, flags, E, N);
        gemm_kernel<<<2048, 512, 0, stream>>>(agg, deg, x, Wl32, bl32, Wr32,
                                              d_out, col_sum, col_sq, flags, N);
        ChemSageBlock_89206470738295_kernel<<<(int)((nd / 4 + 255) / 256), 256, 0, stream>>>(
            d_out, col_sum, col_sq, gm32, bt32, flags, N, nd);
    }
}